// Round 1
// baseline (1569.602 us; speedup 1.0000x reference)
//
#include <hip/hip_runtime.h>
#include <math.h>

// CRF log-likelihood, B=512, S=512, T=128.
// ROUND 10: ONE WAVE PER BATCH, ZERO BARRIERS. R9 measured 1222 cyc/step;
// decomposition: __syncthreads (vmcnt(0)+lgkmcnt(0) drain of the emission
// prefetch + 4-wave sync skew) ~300, sref ds_read ~120, 4-deep DS-based
// shfl chain ~200, LDS roundtrip ~180. All structural costs of the 4-wave
// layout. New layout: 64 lanes own the whole 128x128 step:
//   lane = rg(0..7) x cg(0..7); rows 16rg..16rg+15, cols 16cg..16cg+15.
//   E=exp(trans) fragment lives in REGISTERS (128 v2f/lane, ~350 VGPR,
//   __launch_bounds__(64,1) -> 512-reg budget, 2 waves/CU is all we need).
//   p exchange through 512B LDS, single buffer: DS ops of ONE wave are
//   processed in order -> ds_write then ds_read needs NO s_barrier, and
//   no vmcnt drain ever (prefetch latency truly hidden).
//   Normalizer sref = p[0] via readfirstlane (lane 0 owns cols {0,1}),
//   off the LDS path. Reduce over 8 rg = 3 value-routed stages:
//   xor1/xor2 as DPP quad_perm (VALU latency), xor4 as ds_swizzle.
// Arithmetic stream (chunk rotation (k+rg)&3, 8-deep pk_fma chain, same
// balanced butterfly tree, emv*cc then t*f, double Ld) matches R9 term
// for term -> per-step results bit-identical; only tail reductions
// reassociate. Read pattern: 2-way bank alias (free, m136); writes are a
// perfect 64xb64 permutation (conflict-free).

#define T 128
#define SLEN 512
#define BATCH 512

typedef float v2f __attribute__((ext_vector_type(2)));

__device__ __forceinline__ float dpp_xor1(float x) {
    // quad_perm [1,0,3,2] == lane ^ 1
    return __int_as_float(__builtin_amdgcn_update_dpp(
        0, __float_as_int(x), 0xB1, 0xF, 0xF, true));
}
__device__ __forceinline__ float dpp_xor2(float x) {
    // quad_perm [2,3,0,1] == lane ^ 2
    return __int_as_float(__builtin_amdgcn_update_dpp(
        0, __float_as_int(x), 0x4E, 0xF, 0xF, true));
}
__device__ __forceinline__ float swz_xor4(float x) {
    // BitMode: and=0x1F, or=0, xor=4
    return __int_as_float(__builtin_amdgcn_ds_swizzle(__float_as_int(x), 0x101F));
}

__global__ __launch_bounds__(64, 1) void fwd_kernel(
    const float* __restrict__ em, const int* __restrict__ tags,
    const int* __restrict__ mask, const float* __restrict__ startT,
    const float* __restrict__ endT, const float* __restrict__ trans,
    float* __restrict__ ws)
{
    const int tid = threadIdx.x;   // 0..63
    const int rg  = tid & 7;       // row group: rows 16rg..16rg+15
    const int cg  = tid >> 3;      // col group: cols 16cg..16cg+15
    const int b   = blockIdx.x;
    const int rb0 = rg & 1, rb1 = (rg >> 1) & 1, rb2 = (rg >> 2) & 1;
    // After 3 routed butterfly stages this lane ends with cols {c2, c2+1}:
    const int c2  = 16 * cg + 8 * rb0 + 4 * rb1 + 2 * rb2;

    const float* emb = em + (size_t)b * SLEN * T;
    const int*   mk  = mask + (size_t)b * SLEN;

    __shared__ __align__(16) float p_lds[T];   // 512 B, single buffer

    // Rotated row-chunk schedule (matches R9's (i+rg)&3 accumulation order).
    int rbase[4];
#pragma unroll
    for (int k = 0; k < 4; ++k)
        rbase[k] = 16 * rg + 4 * ((k + rg) & 3);

    // E fragment: E2[k][rp][c] = (exp(trans[r][col]), exp(trans[r+1][col]))
    // for r = rbase[k] + 2*rp, col = 16cg + c.  128 v2f = 256 VGPRs.
    v2f E2[4][2][16];
#pragma unroll
    for (int k = 0; k < 4; ++k) {
#pragma unroll
        for (int rp = 0; rp < 2; ++rp) {
            const float* t0p = trans + (rbase[k] + 2 * rp) * T + 16 * cg;
            const float* t1p = t0p + T;
#pragma unroll
            for (int c = 0; c < 16; ++c)
                E2[k][rp][c] = (v2f){ __expf(t0p[c]), __expf(t1p[c]) };
        }
    }

    const v2f eend = (v2f){ __expf(endT[c2]), __expf(endT[c2 + 1]) };

    // alpha_0 in linear domain; write p0 (wave-internal order, no barrier).
    v2f pprev = (v2f){ __expf(startT[c2]     + emb[c2]),
                       __expf(startT[c2 + 1] + emb[c2 + 1]) };
    *(v2f*)&p_lds[c2] = pprev;
    double Ld = 0.0;

    // 4-deep emission/mask prefetch; exp applied off-chain.
    v2f emv[4], emn[4];
    int mkv[4], mkn[4];
#pragma unroll
    for (int k = 0; k < 4; ++k) {
        const v2f raw = *(const v2f*)(emb + (1 + k) * T + c2);
        emv[k] = (v2f){ __expf(raw.x), __expf(raw.y) };
        mkv[k] = mk[1 + k];
    }

    for (int s0 = 1; s0 < SLEN; s0 += 4) {
#pragma unroll
        for (int k = 0; k < 4; ++k) {
            int ss = s0 + 4 + k; ss = (ss < SLEN) ? ss : (SLEN - 1);  // uniform
            emn[k] = *(const v2f*)(emb + ss * T + c2);
            mkn[k] = mk[ss];
        }
#pragma unroll
        for (int k = 0; k < 4; ++k) {
            const int s = s0 + k;
            if (s < SLEN) {                       // uniform guard (511 steps)
                // Normalizer: col 0 of previous step lives in lane 0's pprev.x.
                const float sref = fmaxf(__int_as_float(
                    __builtin_amdgcn_readfirstlane(__float_as_int(pprev.x))),
                    1e-30f);
                const float cc = __builtin_amdgcn_rcpf(sref);
                Ld += (double)__logf(sref);       // exact accounting

                // p chunks (2-way bank alias: free).
                v2f pk0[4], pk1[4];
#pragma unroll
                for (int kk = 0; kk < 4; ++kk) {
                    const float4 pv = *(const float4*)&p_lds[rbase[kk]];
                    pk0[kk] = (v2f){ pv.x, pv.y };
                    pk1[kk] = (v2f){ pv.z, pv.w };
                }
                // 128 pk_fma: 16 cols x 8-deep row-pair chains.
                v2f acc[16];
#pragma unroll
                for (int c = 0; c < 16; ++c)
                    acc[c] = pk0[0] * E2[0][0][c];
#pragma unroll
                for (int c = 0; c < 16; ++c)
                    acc[c] = __builtin_elementwise_fma(pk1[0], E2[0][1][c], acc[c]);
#pragma unroll
                for (int kk = 1; kk < 4; ++kk) {
#pragma unroll
                    for (int c = 0; c < 16; ++c) {
                        acc[c] = __builtin_elementwise_fma(pk0[kk], E2[kk][0][c], acc[c]);
                        acc[c] = __builtin_elementwise_fma(pk1[kk], E2[kk][1][c], acc[c]);
                    }
                }
                float sv[16];
#pragma unroll
                for (int c = 0; c < 16; ++c) sv[c] = acc[c].x + acc[c].y;

                // Value-routed reduce over 8 rg lanes (3 stages).
                float v1[8];
#pragma unroll
                for (int c = 0; c < 8; ++c)
                    v1[c] = (rb0 ? sv[c + 8] : sv[c])
                          + dpp_xor1(rb0 ? sv[c] : sv[c + 8]);
                float v2_[4];
#pragma unroll
                for (int c = 0; c < 4; ++c)
                    v2_[c] = (rb1 ? v1[c + 4] : v1[c])
                           + dpp_xor2(rb1 ? v1[c] : v1[c + 4]);
                const float t0 = (rb2 ? v2_[2] : v2_[0])
                               + swz_xor4(rb2 ? v2_[0] : v2_[2]);
                const float t1 = (rb2 ? v2_[3] : v2_[1])
                               + swz_xor4(rb2 ? v2_[1] : v2_[3]);

                // Linear-domain update; mask=0 keeps alpha (scaled by cc only).
                const v2f pn = (v2f){ t0 * (emv[k].x * cc),
                                      t1 * (emv[k].y * cc) };
                const v2f pm = (v2f){ pprev.x * cc, pprev.y * cc };
                pprev = (mkv[k] > 0) ? pn : pm;
                *(v2f*)&p_lds[c2] = pprev;        // perfect 64xb64 permutation
            }
        }
#pragma unroll
        for (int k = 0; k < 4; ++k) {
            emv[k] = (v2f){ __expf(emn[k].x), __expf(emn[k].y) };
            mkv[k] = mkn[k];
        }
    }

    // ---- denominator: log(sum_j p_j e^endT_j) + Ld ----
    float sm = pprev.x * eend.x + pprev.y * eend.y;
#pragma unroll
    for (int off = 32; off; off >>= 1) sm += __shfl_xor(sm, off);

    // ---- numerator: 8 strided steps per lane ----
    const int* tg = tags + (size_t)b * SLEN;
    float nv = 0.f; int cnt = 0;
#pragma unroll
    for (int rep = 0; rep < 8; ++rep) {
        const int s = tid + 64 * rep;
        const int mm = mk[s];
        cnt += (mm != 0);
        if (s >= 1 && mm > 0)
            nv += trans[tg[s - 1] * T + tg[s]] + emb[s * T + tg[s]];
    }
#pragma unroll
    for (int off = 32; off; off >>= 1) {
        nv  += __shfl_xor(nv, off);
        cnt += __shfl_xor(cnt, off);
    }
    if (tid == 0) {
        const float denom = __logf(sm) + (float)Ld;
        const int t0g = tg[0], tl = tg[cnt - 1];
        ws[b] = (startT[t0g] + emb[t0g] + endT[tl] + nv) - denom;
    }
}

__global__ __launch_bounds__(256) void reduce_kernel(
    const float* __restrict__ ws, float* __restrict__ out)
{
    const int t = threadIdx.x;          // one block of 256
    float local = 0.f;
    for (int i = t; i < BATCH; i += 256) local += ws[i];
    __shared__ float rf[256];
    rf[t] = local;
    __syncthreads();
    for (int off = 128; off > 0; off >>= 1) {
        if (t < off) rf[t] += rf[t + off];
        __syncthreads();
    }
    if (t == 0) out[0] = rf[0];
}

extern "C" void kernel_launch(void* const* d_in, const int* in_sizes, int n_in,
                              void* d_out, int out_size, void* d_ws, size_t ws_size,
                              hipStream_t stream)
{
    const float* emissions = (const float*)d_in[0];
    const int*   tags      = (const int*)d_in[1];
    const int*   mask      = (const int*)d_in[2];
    const float* startT    = (const float*)d_in[3];
    const float* endT      = (const float*)d_in[4];
    const float* trans     = (const float*)d_in[5];
    float* out = (float*)d_out;
    float* ws  = (float*)d_ws;          // BATCH floats of per-batch partials

    fwd_kernel<<<BATCH, 64, 0, stream>>>(emissions, tags, mask, startT, endT, trans, ws);
    reduce_kernel<<<1, 256, 0, stream>>>(ws, out);
}

// Round 2
// 449.377 us; speedup vs baseline: 3.4928x; 3.4928x over previous
//
#include <hip/hip_runtime.h>
#include <math.h>

// CRF log-likelihood, B=512, S=512, T=128.
// ROUND 11: 2 WAVES/BATCH + lgkm-only barrier. R10 post-mortem: VALU can
// only address 256 VGPRs (v0-v255); E=256 regs spilled to scratch
// (WRITE_SIZE 16KB->22.7MB, dur 260->1453us). Fix: each wave owns 64 output
// cols -> E/lane = 16 rows x 8 cols = 128 VGPRs, total ~205, no spill.
// Cross-wave exchange via 2x512B LDS double buffer; sync via inline-asm
//   s_waitcnt lgkmcnt(0); s_barrier
// which (unlike __syncthreads) does NOT drain vmcnt -> 4-deep emission
// prefetch stays in flight across the barrier. 2-wave skew << R9's 4-wave.
// p storage swizzle slot(j) = j ^ (((j>>5)&3)<<2): all 4 b128 chunk reads
// hit 32 distinct banks (verified per-rg on paper); writes 2-way (free).
// Reduce over 8 rg = 3 stages: DPP quad_perm xor1, xor2 (VALU latency),
// ds_swizzle xor4. Each lane ends owning exactly 1 column (scalar pprev);
// normalizer sref = broadcast ds_read of col 0 (off critical path).
// Linear-domain recursion with exact accounting (Ld += log sref, double)
// unchanged from R9/R10 (both verified absmax 0.0).

#define T 128
#define SLEN 512
#define BATCH 512

typedef float v2f __attribute__((ext_vector_type(2)));

static __device__ __forceinline__ float dpp_xor1(float x) {
    // quad_perm [1,0,3,2] == lane ^ 1
    return __int_as_float(__builtin_amdgcn_update_dpp(
        0, __float_as_int(x), 0xB1, 0xF, 0xF, true));
}
static __device__ __forceinline__ float dpp_xor2(float x) {
    // quad_perm [2,3,0,1] == lane ^ 2
    return __int_as_float(__builtin_amdgcn_update_dpp(
        0, __float_as_int(x), 0x4E, 0xF, 0xF, true));
}
static __device__ __forceinline__ float swz_xor4(float x) {
    // BitMode: and=0x1F, or=0, xor=4
    return __int_as_float(__builtin_amdgcn_ds_swizzle(__float_as_int(x), 0x101F));
}
static __device__ __forceinline__ void lgkm_barrier() {
    // LDS-writes-drained barrier that leaves vmcnt (global prefetch) alone.
    asm volatile("s_waitcnt lgkmcnt(0)\n\ts_barrier" ::: "memory");
}
// Bank swizzle for the 128-word p buffer: 4-word groups xor'd by (j>>5).
static __device__ __forceinline__ int pslot(int j) {
    return j ^ (((j >> 5) & 3) << 2);
}

__global__ __launch_bounds__(128, 1) void fwd_kernel(
    const float* __restrict__ em, const int* __restrict__ tags,
    const int* __restrict__ mask, const float* __restrict__ startT,
    const float* __restrict__ endT, const float* __restrict__ trans,
    float* __restrict__ ws)
{
    const int tid  = threadIdx.x;      // 0..127
    const int lane = tid & 63;
    const int w    = tid >> 6;         // wave 0/1: output cols 64w..64w+63
    const int rg   = lane & 7;         // row group: rows 16rg..16rg+15
    const int cg   = lane >> 3;        // col group: cols 64w+8cg..+7
    const int b    = blockIdx.x;
    const int rb0  = rg & 1, rb1 = (rg >> 1) & 1, rb2 = (rg >> 2) & 1;
    // After the 3 routed butterfly stages this lane owns exactly this col:
    const int mycol = 64 * w + 8 * cg + 4 * rb0 + 2 * rb1 + rb2;

    const float* emb = em + (size_t)b * SLEN * T;
    const int*   mk  = mask + (size_t)b * SLEN;

    __shared__ __align__(16) float p_lds[2][T];   // double buffer, 1 KB
    __shared__ float reds[2], redn[2];
    __shared__ int   redc[2];

    // Rotated row-chunk schedule + swizzled read slots.
    int rbase[4], rslot[4];
#pragma unroll
    for (int k = 0; k < 4; ++k) {
        rbase[k] = 16 * rg + 4 * ((k + rg) & 3);
        rslot[k] = pslot(rbase[k]);    // 4-word group shares one xor
    }
    const int wslot = pslot(mycol);

    // E fragment: Elo[k][c] = (exp(trans[r0][col]), exp(trans[r0+1][col])),
    // Ehi = rows (r0+2, r0+3); r0 = rbase[k], col = 64w + 8cg + c.
    // 64 v2f = 128 VGPRs.
    v2f Elo[4][8], Ehi[4][8];
    {
        const int cb = 64 * w + 8 * cg;
#pragma unroll
        for (int k = 0; k < 4; ++k) {
            const float* t0p = trans + (rbase[k] + 0) * T + cb;
            const float* t1p = t0p + T;
            const float* t2p = t1p + T;
            const float* t3p = t2p + T;
#pragma unroll
            for (int c = 0; c < 8; ++c) {
                Elo[k][c] = (v2f){ __expf(t0p[c]), __expf(t1p[c]) };
                Ehi[k][c] = (v2f){ __expf(t2p[c]), __expf(t3p[c]) };
            }
        }
    }
    const float eendv = __expf(endT[mycol]);

    // alpha_0 in linear domain; step 1 reads buffer 1.
    float pprev = __expf(startT[mycol] + emb[mycol]);
    p_lds[1][wslot] = pprev;
    double Ld = 0.0;

    // 4-deep emission/mask prefetch; exp applied off-chain.
    float emv[4], emn[4];
    int   mkv[4], mkn[4];
#pragma unroll
    for (int k = 0; k < 4; ++k) {
        emv[k] = __expf(emb[(1 + k) * T + mycol]);
        mkv[k] = mk[1 + k];
    }
    lgkm_barrier();

    for (int s0 = 1; s0 < SLEN; s0 += 4) {
#pragma unroll
        for (int k = 0; k < 4; ++k) {
            int ss = s0 + 4 + k; ss = (ss < SLEN) ? ss : (SLEN - 1);  // uniform
            emn[k] = emb[ss * T + mycol];
            mkn[k] = mk[ss];
        }
#pragma unroll
        for (int k = 0; k < 4; ++k) {
            const int s = s0 + k;
            if (s < SLEN) {                       // uniform guard (511 steps)
                const int cur = (1 + k) & 1;      // == s&1, compile-time
                // Off-chain normalizer: col 0 (slot 0) of input buffer.
                const float sref0 = p_lds[cur][0];
                const float srefc = fmaxf(sref0, 1e-30f);
                const float cc = __builtin_amdgcn_rcpf(srefc);
                Ld += (double)__logf(srefc);      // exact accounting

                // p chunks (swizzled slots: conflict-free b128 reads).
                v2f pk0[4], pk1[4];
#pragma unroll
                for (int kk = 0; kk < 4; ++kk) {
                    const float4 pv = *(const float4*)&p_lds[cur][rslot[kk]];
                    pk0[kk] = (v2f){ pv.x, pv.y };
                    pk1[kk] = (v2f){ pv.z, pv.w };
                }
                // 64 pk_fma: 8 cols x 8-deep row-pair chains.
                v2f acc[8];
#pragma unroll
                for (int c = 0; c < 8; ++c)
                    acc[c] = pk0[0] * Elo[0][c];
#pragma unroll
                for (int c = 0; c < 8; ++c)
                    acc[c] = __builtin_elementwise_fma(pk1[0], Ehi[0][c], acc[c]);
#pragma unroll
                for (int kk = 1; kk < 4; ++kk) {
#pragma unroll
                    for (int c = 0; c < 8; ++c) {
                        acc[c] = __builtin_elementwise_fma(pk0[kk], Elo[kk][c], acc[c]);
                        acc[c] = __builtin_elementwise_fma(pk1[kk], Ehi[kk][c], acc[c]);
                    }
                }
                float sv[8];
#pragma unroll
                for (int c = 0; c < 8; ++c) sv[c] = acc[c].x + acc[c].y;

                // Value-routed reduce over 8 rg lanes (3 stages).
                float v1[4];
#pragma unroll
                for (int c = 0; c < 4; ++c)
                    v1[c] = (rb0 ? sv[c + 4] : sv[c])
                          + dpp_xor1(rb0 ? sv[c] : sv[c + 4]);
                float v2_[2];
#pragma unroll
                for (int c = 0; c < 2; ++c)
                    v2_[c] = (rb1 ? v1[c + 2] : v1[c])
                           + dpp_xor2(rb1 ? v1[c] : v1[c + 2]);
                const float t = (rb2 ? v2_[1] : v2_[0])
                              + swz_xor4(rb2 ? v2_[0] : v2_[1]);

                // Linear-domain update; mask=0 keeps alpha (scaled by cc).
                const float pn = t * (emv[k] * cc);
                const float pm = pprev * cc;
                pprev = (mkv[k] > 0) ? pn : pm;
                p_lds[cur ^ 1][wslot] = pprev;
                lgkm_barrier();                   // no vmcnt drain
            }
        }
#pragma unroll
        for (int k = 0; k < 4; ++k) { emv[k] = __expf(emn[k]); mkv[k] = mkn[k]; }
    }

    // ---- denominator: log(sum_j p_j e^endT_j) + Ld ----
    float sm = pprev * eendv;
#pragma unroll
    for (int off = 32; off; off >>= 1) sm += __shfl_xor(sm, off);
    if (lane == 0) reds[w] = sm;

    // ---- numerator: 4 strided steps per thread ----
    const int* tg = tags + (size_t)b * SLEN;
    float nv = 0.f; int cnt = 0;
#pragma unroll
    for (int rep = 0; rep < 4; ++rep) {
        const int s = tid + 128 * rep;
        const int mm = mk[s];
        cnt += (mm != 0);
        if (s >= 1 && mm > 0)
            nv += trans[tg[s - 1] * T + tg[s]] + emb[s * T + tg[s]];
    }
#pragma unroll
    for (int off = 32; off; off >>= 1) {
        nv  += __shfl_xor(nv, off);
        cnt += __shfl_xor(cnt, off);
    }
    if (lane == 0) { redn[w] = nv; redc[w] = cnt; }
    __syncthreads();
    if (tid == 0) {
        const float ssum = reds[0] + reds[1];
        const float nsum = redn[0] + redn[1];
        const int seqlen = redc[0] + redc[1];
        const float denom = __logf(ssum) + (float)Ld;
        const int t0g = tg[0], tl = tg[seqlen - 1];
        ws[b] = (startT[t0g] + emb[t0g] + endT[tl] + nsum) - denom;
    }
}

__global__ __launch_bounds__(256) void reduce_kernel(
    const float* __restrict__ ws, float* __restrict__ out)
{
    const int t = threadIdx.x;          // one block of 256
    float local = 0.f;
    for (int i = t; i < BATCH; i += 256) local += ws[i];
    __shared__ float rf[256];
    rf[t] = local;
    __syncthreads();
    for (int off = 128; off > 0; off >>= 1) {
        if (t < off) rf[t] += rf[t + off];
        __syncthreads();
    }
    if (t == 0) out[0] = rf[0];
}

extern "C" void kernel_launch(void* const* d_in, const int* in_sizes, int n_in,
                              void* d_out, int out_size, void* d_ws, size_t ws_size,
                              hipStream_t stream)
{
    const float* emissions = (const float*)d_in[0];
    const int*   tags      = (const int*)d_in[1];
    const int*   mask      = (const int*)d_in[2];
    const float* startT    = (const float*)d_in[3];
    const float* endT      = (const float*)d_in[4];
    const float* trans     = (const float*)d_in[5];
    float* out = (float*)d_out;
    float* ws  = (float*)d_ws;          // BATCH floats of per-batch partials

    fwd_kernel<<<BATCH, 128, 0, stream>>>(emissions, tags, mask, startT, endT, trans, ws);
    reduce_kernel<<<1, 256, 0, stream>>>(ws, out);
}